// Round 12
// baseline (2114.518 us; speedup 1.0000x reference)
//
#include <hip/hip_runtime.h>
#include <math.h>

#define FF 2048
#define NL 12
#define NB 16
#define TT 32
#define EPS 1e-5f
#define LOG2E 1.44269504088896f
#define WPL 3584   // float4 per layer: 7 blocks of 512 f-quads

typedef float v2f __attribute__((ext_vector_type(2)));
__device__ __forceinline__ v2f mk2(float x){ v2f r; r.x = x; r.y = x; return r; }

// ---------------------------------------------------------------------------
// Prepack into d_ws as w_all[24][3584] float4, f-QUAD layout (28 B per f):
//   [   0.. 511] w0 quad   {w0[4q..4q+3]}
//   [ 512..1023] w1 quad
//   [1024..1535] w2 quad
//   [1536..2047] b  quad
//   [2048..2559] u0 quad
//   [2560..3071] u1 quad
//   [3072..3583] u2 quad
// Layers 0..11 = encoder, 12..23 = decoder.
// ---------------------------------------------------------------------------
__global__ __launch_bounds__(256) void prepack_kernel(
    const float* __restrict__ enc_l1_w, const float* __restrict__ enc_l1_b,
    const float* __restrict__ enc_l2_w,
    const float* __restrict__ dec_l1_w, const float* __restrict__ dec_l1_b,
    const float* __restrict__ dec_l2_w,
    float4* __restrict__ w_all)
{
    int idx = blockIdx.x * blockDim.x + threadIdx.x;
    if (idx >= 24 * 512) return;
    int lay = idx >> 9;
    int fq  = idx & 511;
    int f0  = 4*fq;
    const float *w1, *b1, *w2;
    if (lay < NL) {
        w1 = enc_l1_w + (size_t)lay * FF * 3;
        b1 = enc_l1_b + (size_t)lay * FF;
        w2 = enc_l2_w + (size_t)lay * 3 * FF;
    } else {
        int l = lay - NL;
        w1 = dec_l1_w + (size_t)l * FF * 3;
        b1 = dec_l1_b + (size_t)l * FF;
        w2 = dec_l2_w + (size_t)l * 3 * FF;
    }
    float4* base = w_all + (size_t)lay * WPL;
    base[        fq] = make_float4(w1[f0*3+0], w1[(f0+1)*3+0], w1[(f0+2)*3+0], w1[(f0+3)*3+0]);
    base[ 512 + fq] = make_float4(w1[f0*3+1], w1[(f0+1)*3+1], w1[(f0+2)*3+1], w1[(f0+3)*3+1]);
    base[1024 + fq] = make_float4(w1[f0*3+2], w1[(f0+1)*3+2], w1[(f0+2)*3+2], w1[(f0+3)*3+2]);
    base[1536 + fq] = make_float4(b1[f0], b1[f0+1], b1[f0+2], b1[f0+3]);
    base[2048 + fq] = make_float4(w2[f0], w2[f0+1], w2[f0+2], w2[f0+3]);
    base[2560 + fq] = make_float4(w2[FF+f0], w2[FF+f0+1], w2[FF+f0+2], w2[FF+f0+3]);
    base[3072 + fq] = make_float4(w2[2*FF+f0], w2[2*FF+f0+1], w2[2*FF+f0+2], w2[2*FF+f0+3]);
}

// ---------------------------------------------------------------------------
// Main kernel: one block per batch element, 1024 threads (16 waves).
// ---------------------------------------------------------------------------
struct __align__(16) SharedMem {
    float4 wbuf[2][WPL];   // double-buffered layer weights (112 KB)
    float4 x4[TT];         // activations
    float4 fred2[TT][4];   // FFN partials: [t][wave-group] = {r0,r1,r2,0}
    float4 outst[TT];      // decoder predictions
    float4 mem4[TT];       // encoder output
    float  kk[3][TT];      // self-attn keys, head-major
    float  vv[3][TT];      // self-attn values
    float4 oo[TT];         // SA attention outputs {h0,h1,h2,-}
    float4 oo2[TT];        // CA attention outputs
    float  ck[NL][3][TT];  // cross-attn keys per decoder layer
    float  cv[NL][3][TT];  // cross-attn values
};

__device__ __forceinline__ void ln3s(float y0, float y1, float y2,
    const float* __restrict__ w, const float* __restrict__ b,
    float& o0, float& o1, float& o2)
{
    float m  = (y0 + y1 + y2) * (1.0f / 3.0f);
    float d0 = y0 - m, d1 = y1 - m, d2 = y2 - m;
    float v  = (d0*d0 + d1*d1 + d2*d2) * (1.0f / 3.0f);
    float r  = __builtin_amdgcn_rsqf(v + EPS);
    o0 = d0 * r * w[0] + b[0];
    o1 = d1 * r * w[1] + b[1];
    o2 = d2 * r * w[2] + b[2];
}

template<int CTRL>
__device__ __forceinline__ float dpp_add(float v)
{
    int sh = __builtin_amdgcn_update_dpp(0, __float_as_int(v), CTRL, 0xF, 0xF, true);
    return v + __int_as_float(sh);
}

__device__ __forceinline__ float wave_sum64(float v)
{
    v = dpp_add<0x111>(v);
    v = dpp_add<0x112>(v);
    v = dpp_add<0x114>(v);
    v = dpp_add<0x118>(v);
    v = dpp_add<0x142>(v);
    v = dpp_add<0x143>(v);
    return v;   // valid in lane 63
}

// Combine helper: sum the 4 wave-group partials for token q.
__device__ __forceinline__ void fred_sum(const SharedMem& s, int q,
                                         float& f0, float& f1, float& f2)
{
    float4 p0 = s.fred2[q][0];
    float4 p1 = s.fred2[q][1];
    float4 p2 = s.fred2[q][2];
    float4 p3 = s.fred2[q][3];
    f0 = (p0.x + p1.x) + (p2.x + p3.x);
    f1 = (p0.y + p1.y) + (p2.y + p3.y);
    f2 = (p0.z + p1.z) + (p2.z + p3.z);
}

// Halved-range softmax-attention: lanes 0-31 handle keys 0..15, lanes 32-63
// keys 16..31; partials combined via shfl_xor(32). qs has log2e folded.
template<bool MASK>
__device__ __forceinline__ float attn_half(float qs,
    const float* __restrict__ k, const float* __restrict__ v,
    int half, int ntok, int rep, float repw)
{
    const float4* k4 = (const float4*)k;
    const float4* v4 = (const float4*)v;
    float den0 = 0.f, den1 = 0.f, nv0 = 0.f, nv1 = 0.f;
    #pragma unroll
    for (int jb = 0; jb < 4; ++jb) {
        float4 kq = k4[half*4 + jb];
        float4 vq = v4[half*4 + jb];
        const float kj[4] = {kq.x, kq.y, kq.z, kq.w};
        const float vj[4] = {vq.x, vq.y, vq.z, vq.w};
        #pragma unroll
        for (int u = 0; u < 4; ++u) {
            float w = exp2f(qs * kj[u]);
            if (MASK) {
                const int j = half*16 + jb*4 + u;
                w = (j < ntok) ? w : 0.f;
                w = (j == rep) ? w * repw : w;
            }
            if (jb & 1) { den1 += w; nv1 = fmaf(w, vj[u], nv1); }
            else        { den0 += w; nv0 = fmaf(w, vj[u], nv0); }
        }
    }
    float den = den0 + den1;
    float nv  = nv0 + nv1;
    den += __shfl_xor(den, 32, 64);
    nv  += __shfl_xor(nv , 32, 64);
    return nv * __builtin_amdgcn_rcpf(den);
}

// FFN: 4 token groups x 256 f-lanes, 2 f-quads per thread, packed fp32 math,
// f-quad weights from LDS (14 b128 loads/thread), DPP reduction, one b128
// partial store per (token) from lane 63.
template<int NII>
__device__ __forceinline__ void ffn_body(SharedMem& s, int tid,
    const float4* __restrict__ wb)
{
    const int flane = tid & 255;
    const int g     = tid >> 8;
    const int w4    = (tid >> 6) & 3;
    const int lane  = tid & 63;
    const v2f z2 = {0.f, 0.f};
    float X0[NII], X1[NII], X2[NII];
    v2f ac0[NII], ac1[NII], ac2[NII];
    #pragma unroll
    for (int ii = 0; ii < NII; ++ii) {
        float4 xt = s.x4[g + 4*ii];
        X0[ii] = xt.x; X1[ii] = xt.y; X2[ii] = xt.z;
        ac0[ii] = z2; ac1[ii] = z2; ac2[ii] = z2;
    }
    #pragma unroll
    for (int jp = 0; jp < 2; ++jp) {
        const int fq = flane + 256*jp;
        float4 W0 = wb[fq],        W1 = wb[ 512+fq];
        float4 W2 = wb[1024+fq],   Bq = wb[1536+fq];
        float4 U0 = wb[2048+fq],   U1 = wb[2560+fq];
        float4 U2 = wb[3072+fq];
        v2f w0l={W0.x,W0.y}, w0h={W0.z,W0.w};
        v2f w1l={W1.x,W1.y}, w1h={W1.z,W1.w};
        v2f w2l={W2.x,W2.y}, w2h={W2.z,W2.w};
        v2f bl ={Bq.x,Bq.y}, bh ={Bq.z,Bq.w};
        v2f u0l={U0.x,U0.y}, u0h={U0.z,U0.w};
        v2f u1l={U1.x,U1.y}, u1h={U1.z,U1.w};
        v2f u2l={U2.x,U2.y}, u2h={U2.z,U2.w};
        #pragma unroll
        for (int ii = 0; ii < NII; ++ii) {
            v2f x0 = mk2(X0[ii]), x1 = mk2(X1[ii]), x2 = mk2(X2[ii]);
            v2f hl = __builtin_elementwise_fma(w0l, x0,
                     __builtin_elementwise_fma(w1l, x1,
                     __builtin_elementwise_fma(w2l, x2, bl)));
            v2f hh = __builtin_elementwise_fma(w0h, x0,
                     __builtin_elementwise_fma(w1h, x1,
                     __builtin_elementwise_fma(w2h, x2, bh)));
            hl = __builtin_elementwise_max(hl, z2);
            hh = __builtin_elementwise_max(hh, z2);
            ac0[ii] = __builtin_elementwise_fma(u0l, hl, ac0[ii]);
            ac0[ii] = __builtin_elementwise_fma(u0h, hh, ac0[ii]);
            ac1[ii] = __builtin_elementwise_fma(u1l, hl, ac1[ii]);
            ac1[ii] = __builtin_elementwise_fma(u1h, hh, ac1[ii]);
            ac2[ii] = __builtin_elementwise_fma(u2l, hl, ac2[ii]);
            ac2[ii] = __builtin_elementwise_fma(u2h, hh, ac2[ii]);
        }
    }
    #pragma unroll
    for (int ii = 0; ii < NII; ++ii) {
        const int t = g + 4*ii;
        float r0 = wave_sum64(ac0[ii].x + ac0[ii].y);
        float r1 = wave_sum64(ac1[ii].x + ac1[ii].y);
        float r2 = wave_sum64(ac2[ii].x + ac2[ii].y);
        if (lane == 63)
            s.fred2[t][w4] = make_float4(r0, r1, r2, 0.f);
    }
}

// One transformer layer (R11 phase structure).
// P1: waves 0-2 combine+SA->oo | waves 3-15 prefetch half A.   barrier
// P2: waves 0-2 SA out-proj + LN1 -> B (redundant); if CA: CA -> oo2; else
//     wave0 writes x4. | waves 3-15 prefetch half B.           barrier
// P3 (CA only): wave0 CA out-proj + LN2 -> x4.                 barrier
// P4: FFN (all 16 waves).                                      barrier
template<bool HAS_CA, bool MASK_SA>
__device__ __forceinline__ void run_layer(SharedMem& s, int tid,
    int ntok, int rep, float repw, int do_combine, int p,
    const float4* __restrict__ nw,
    const float* __restrict__ saw, const float* __restrict__ sab,
    const float* __restrict__ saow, const float* __restrict__ saob,
    const float* __restrict__ n1w, const float* __restrict__ n1b,
    const float* __restrict__ caw, const float* __restrict__ cab,
    const float* __restrict__ caow, const float* __restrict__ caob,
    const float* __restrict__ n2w, const float* __restrict__ n2b,
    const float* __restrict__ ckh, const float* __restrict__ cvh,
    const float* __restrict__ pl2b, const float* __restrict__ pnw,
    const float* __restrict__ pnb)
{
    const int wv   = tid >> 6;
    const int lane = tid & 63;
    const int q    = lane & 31;
    const int half = lane >> 5;
    float X0 = 0.f, X1 = 0.f, X2 = 0.f;
    float B0 = 0.f, B1 = 0.f, B2 = 0.f;

    // ---------------- P1 ----------------
    if (wv >= 3) {
        for (int k = tid - 192; k < 1792; k += 832)
            s.wbuf[p ^ 1][k] = nw[k];
    } else {
        const int h = wv;
        float4 xa = s.x4[q];
        if (do_combine) {
            float f0, f1, f2;
            fred_sum(s, q, f0, f1, f2);
            ln3s(xa.x + f0 + pl2b[0], xa.y + f1 + pl2b[1],
                 xa.z + f2 + pl2b[2], pnw, pnb, X0, X1, X2);
        } else { X0 = xa.x; X1 = xa.y; X2 = xa.z; }
        if (lane < 32 && q < ntok) {
            s.kk[h][q] = sab[3+h] + saw[9+3*h]*X0  + saw[10+3*h]*X1 + saw[11+3*h]*X2;
            s.vv[h][q] = sab[6+h] + saw[18+3*h]*X0 + saw[19+3*h]*X1 + saw[20+3*h]*X2;
        }
        float qv = (sab[h] + saw[3*h]*X0 + saw[3*h+1]*X1 + saw[3*h+2]*X2) * LOG2E;
        float o = attn_half<MASK_SA>(qv, s.kk[h], s.vv[h], half, ntok, rep, repw);
        if (lane < 32 && q < ntok) ((float*)&s.oo[q])[h] = o;
    }
    __syncthreads();   // bar1
    // ---------------- P2 ----------------
    if (wv >= 3) {
        for (int k = 1792 + tid - 192; k < WPL; k += 832)
            s.wbuf[p ^ 1][k] = nw[k];
    } else {
        const int h = wv;
        float4 ov = s.oo[q];
        float y0 = X0 + saob[0] + saow[0]*ov.x + saow[1]*ov.y + saow[2]*ov.z;
        float y1 = X1 + saob[1] + saow[3]*ov.x + saow[4]*ov.y + saow[5]*ov.z;
        float y2 = X2 + saob[2] + saow[6]*ov.x + saow[7]*ov.y + saow[8]*ov.z;
        ln3s(y0, y1, y2, n1w, n1b, B0, B1, B2);
        if (!HAS_CA) {
            if (wv == 0 && lane < 32 && q < ntok)
                s.x4[q] = make_float4(B0, B1, B2, 0.f);
        } else {
            float cqv = (cab[h] + caw[3*h]*B0 + caw[3*h+1]*B1 + caw[3*h+2]*B2) * LOG2E;
            float oc = attn_half<false>(cqv, ckh + h*TT, cvh + h*TT, half, TT, -1, 1.f);
            if (lane < 32 && q < ntok) ((float*)&s.oo2[q])[h] = oc;
        }
    }
    __syncthreads();   // bar2
    if (HAS_CA) {
        // ---------------- P3: wave0 CA out-proj + LN2 -> x4 ----------------
        if (wv == 0 && lane < 32 && q < ntok) {
            float4 cv2 = s.oo2[q];
            float y0 = B0 + caob[0] + caow[0]*cv2.x + caow[1]*cv2.y + caow[2]*cv2.z;
            float y1 = B1 + caob[1] + caow[3]*cv2.x + caow[4]*cv2.y + caow[5]*cv2.z;
            float y2 = B2 + caob[2] + caow[6]*cv2.x + caow[7]*cv2.y + caow[8]*cv2.z;
            float a0, a1, a2;
            ln3s(y0, y1, y2, n2w, n2b, a0, a1, a2);
            s.x4[q] = make_float4(a0, a1, a2, 0.f);
        }
        __syncthreads();   // bar3
    }
    // ---------------- P4: FFN ----------------
    const float4* wb = s.wbuf[p];
    if (ntok <= 8)       ffn_body<2>(s, tid, wb);
    else if (ntok <= 16) ffn_body<4>(s, tid, wb);
    else                 ffn_body<8>(s, tid, wb);
    __syncthreads();   // bar4
}

__global__ __launch_bounds__(1024, 4) void seq_kernel(
    const float* __restrict__ src, const float* __restrict__ angle,
    const float* __restrict__ enc_sa_w, const float* __restrict__ enc_sa_b,
    const float* __restrict__ enc_sa_ow, const float* __restrict__ enc_sa_ob,
    const float* __restrict__ enc_l2_b,
    const float* __restrict__ enc_n1_w, const float* __restrict__ enc_n1_b,
    const float* __restrict__ enc_n2_w, const float* __restrict__ enc_n2_b,
    const float* __restrict__ enc_nf_w, const float* __restrict__ enc_nf_b,
    const float* __restrict__ dec_sa_w, const float* __restrict__ dec_sa_b,
    const float* __restrict__ dec_sa_ow, const float* __restrict__ dec_sa_ob,
    const float* __restrict__ dec_ca_w, const float* __restrict__ dec_ca_b,
    const float* __restrict__ dec_ca_ow, const float* __restrict__ dec_ca_ob,
    const float* __restrict__ dec_l2_b,
    const float* __restrict__ dec_n1_w, const float* __restrict__ dec_n1_b,
    const float* __restrict__ dec_n2_w, const float* __restrict__ dec_n2_b,
    const float* __restrict__ dec_n3_w, const float* __restrict__ dec_n3_b,
    const float* __restrict__ dec_nf_w, const float* __restrict__ dec_nf_b,
    const float4* __restrict__ w_all,
    float* __restrict__ out)
{
    __shared__ SharedMem s;
    const int tid = threadIdx.x;
    const int b   = blockIdx.x;

    // ---- init: stage encoder layer 0 weights + build input
    for (int k = tid; k < WPL; k += 1024)
        s.wbuf[0][k] = w_all[k];
    if (tid < TT) {
        float x0 = src[b*64 + tid];
        float x1 = src[b*64 + 32 + tid];
        float x2 = angle[b];
        s.x4[tid] = make_float4(x0, x1, x2, 0.f);
        if (tid == 0) s.outst[0] = make_float4(x0, x1, x2, 0.f);
    }
    __syncthreads();

    int lp = 0;
    // ---- encoder
    for (int i = 0; i < NL; ++i) {
        const float4* nw = w_all + (size_t)((i < 11) ? (i + 1) : 12) * WPL;
        const int pi = (i > 0) ? (i - 1) : 0;
        run_layer<false, false>(s, tid, TT, -1, 1.f, i > 0, lp & 1, nw,
            enc_sa_w + i*27, enc_sa_b + i*9, enc_sa_ow + i*9, enc_sa_ob + i*3,
            enc_n1_w + i*3, enc_n1_b + i*3,
            nullptr, nullptr, nullptr, nullptr, nullptr, nullptr,
            nullptr, nullptr,
            enc_l2_b + pi*3, enc_n2_w + pi*3, enc_n2_b + pi*3);
        ++lp;
    }
    // encoder tail: combine layer 11 + final LN -> mem; rebuild x for step 1
    if (tid < 32) {
        float4 xa = s.x4[tid];
        float f0, f1, f2;
        fred_sum(s, tid, f0, f1, f2);
        float o0, o1, o2, m0, m1, m2;
        ln3s(xa.x + f0 + enc_l2_b[33], xa.y + f1 + enc_l2_b[34],
             xa.z + f2 + enc_l2_b[35], enc_n2_w + 33, enc_n2_b + 33, o0, o1, o2);
        ln3s(o0, o1, o2, enc_nf_w, enc_nf_b, m0, m1, m2);
        s.mem4[tid] = make_float4(m0, m1, m2, 0.f);
        s.x4[tid]   = (tid == 0) ? s.outst[0] : make_float4(0.f, 0.f, 0.f, 0.f);
    }
    __syncthreads();

    // ---- precompute cross-attn K,V for all decoder layers (head-major)
    for (int idx = tid; idx < NL * 96; idx += 1024) {
        const int lyr = idx / 96;
        const int r   = idx - lyr * 96;
        const int hh  = r >> 5;
        const int t   = r & 31;
        const float* w  = dec_ca_w + lyr*27;
        const float* bb = dec_ca_b + lyr*9;
        float4 mr = s.mem4[t];
        s.ck[lyr][hh][t] = bb[3+hh] + w[(3+hh)*3]*mr.x + w[(3+hh)*3+1]*mr.y + w[(3+hh)*3+2]*mr.z;
        s.cv[lyr][hh][t] = bb[6+hh] + w[(6+hh)*3]*mr.x + w[(6+hh)*3+1]*mr.y + w[(6+hh)*3+2]*mr.z;
    }
    __syncthreads();

    // ---- autoregressive decode with zero-token collapse:
    // tokens 0..t-1 real, token t = representative of 32-t identical zeros
    // (softmax multiplicity 32-t); pred[t] = representative output.
    for (int t = 1; t < TT; ++t) {
        const int ntok = t + 1;
        for (int i = 0; i < NL; ++i) {
            const float4* nw = w_all + (size_t)(12 + ((i < 11) ? (i + 1) : 0)) * WPL;
            const int pi = (i > 0) ? (i - 1) : 0;
            run_layer<true, true>(s, tid, ntok, t, (float)(TT - t), i > 0, lp & 1, nw,
                dec_sa_w + i*27, dec_sa_b + i*9, dec_sa_ow + i*9, dec_sa_ob + i*3,
                dec_n1_w + i*3, dec_n1_b + i*3,
                dec_ca_w + i*27, dec_ca_b + i*9, dec_ca_ow + i*9, dec_ca_ob + i*3,
                dec_n2_w + i*3, dec_n2_b + i*3,
                &s.ck[i][0][0], &s.cv[i][0][0],
                dec_l2_b + pi*3, dec_n3_w + pi*3, dec_n3_b + pi*3);
            ++lp;
        }
        // tail: combine layer 11 for token t -> outst[t]; rebuild x
        if (tid < 32) {
            if (tid == 0) {
                float4 xa = s.x4[t];
                float f0, f1, f2;
                fred_sum(s, t, f0, f1, f2);
                float o0, o1, o2, p0, p1, p2;
                ln3s(xa.x + f0 + dec_l2_b[33], xa.y + f1 + dec_l2_b[34],
                     xa.z + f2 + dec_l2_b[35], dec_n3_w + 33, dec_n3_b + 33,
                     o0, o1, o2);
                ln3s(o0, o1, o2, dec_nf_w, dec_nf_b, p0, p1, p2);
                s.outst[t] = make_float4(p0, p1, p2, 0.f);
            }
            s.x4[tid] = (tid <= t) ? s.outst[tid] : make_float4(0.f, 0.f, 0.f, 0.f);
        }
        __syncthreads();
    }

    // ---- write output: out[b, c, t]
    if (tid < TT) {
        float4 o = s.outst[tid];
        out[b*96 +  0 + tid] = o.x;
        out[b*96 + 32 + tid] = o.y;
        out[b*96 + 64 + tid] = o.z;
    }
}

extern "C" void kernel_launch(void* const* d_in, const int* in_sizes, int n_in,
                              void* d_out, int out_size, void* d_ws, size_t ws_size,
                              hipStream_t stream) {
    const float* src      = (const float*)d_in[0];
    const float* angle    = (const float*)d_in[1];
    const float* enc_sa_w = (const float*)d_in[2];
    const float* enc_sa_b = (const float*)d_in[3];
    const float* enc_sa_ow= (const float*)d_in[4];
    const float* enc_sa_ob= (const float*)d_in[5];
    const float* enc_l1_w = (const float*)d_in[6];
    const float* enc_l1_b = (const float*)d_in[7];
    const float* enc_l2_w = (const float*)d_in[8];
    const float* enc_l2_b = (const float*)d_in[9];
    const float* enc_n1_w = (const float*)d_in[10];
    const float* enc_n1_b = (const float*)d_in[11];
    const float* enc_n2_w = (const float*)d_in[12];
    const float* enc_n2_b = (const float*)d_in[13];
    const float* enc_nf_w = (const float*)d_in[14];
    const float* enc_nf_b = (const float*)d_in[15];
    const float* dec_sa_w = (const float*)d_in[16];
    const float* dec_sa_b = (const float*)d_in[17];
    const float* dec_sa_ow= (const float*)d_in[18];
    const float* dec_sa_ob= (const float*)d_in[19];
    const float* dec_ca_w = (const float*)d_in[20];
    const float* dec_ca_b = (const float*)d_in[21];
    const float* dec_ca_ow= (const float*)d_in[22];
    const float* dec_ca_ob= (const float*)d_in[23];
    const float* dec_l1_w = (const float*)d_in[24];
    const float* dec_l1_b = (const float*)d_in[25];
    const float* dec_l2_w = (const float*)d_in[26];
    const float* dec_l2_b = (const float*)d_in[27];
    const float* dec_n1_w = (const float*)d_in[28];
    const float* dec_n1_b = (const float*)d_in[29];
    const float* dec_n2_w = (const float*)d_in[30];
    const float* dec_n2_b = (const float*)d_in[31];
    const float* dec_n3_w = (const float*)d_in[32];
    const float* dec_n3_b = (const float*)d_in[33];
    const float* dec_nf_w = (const float*)d_in[34];
    const float* dec_nf_b = (const float*)d_in[35];

    float4* w_all = (float4*)d_ws;

    prepack_kernel<<<(24 * 512 + 255) / 256, 256, 0, stream>>>(
        enc_l1_w, enc_l1_b, enc_l2_w,
        dec_l1_w, dec_l1_b, dec_l2_w,
        w_all);

    seq_kernel<<<NB, 1024, 0, stream>>>(
        src, angle,
        enc_sa_w, enc_sa_b, enc_sa_ow, enc_sa_ob, enc_l2_b,
        enc_n1_w, enc_n1_b, enc_n2_w, enc_n2_b, enc_nf_w, enc_nf_b,
        dec_sa_w, dec_sa_b, dec_sa_ow, dec_sa_ob,
        dec_ca_w, dec_ca_b, dec_ca_ow, dec_ca_ob, dec_l2_b,
        dec_n1_w, dec_n1_b, dec_n2_w, dec_n2_b, dec_n3_w, dec_n3_b,
        dec_nf_w, dec_nf_b,
        (const float4*)w_all,
        (float*)d_out);
}